// Round 3
// baseline (89.826 us; speedup 1.0000x reference)
//
#include <hip/hip_runtime.h>

#define N 64
#define MARGIN 0.1f
#define WAVES_PER_BLOCK 4
#define NBLOCKS 2048

// closed form (verified R2..R13, absmax 0.0): row_loss = sum_e u_e*(q_e - p_e)
//   p_e = #{k: lab_k < lab_e},  u_e = sc_e - MARGIN*p_e,  q_e = #{k: u_k < u_e}
//
// R14: 2-VALU-op rank step WITHOUT a serial chain.
//   R11: v_sub + v_ashr + v_add = 3 VALU/elem, 4 independent chains (80.2us).
//   R13: ballot+popcount+writelane = 2 VALU/elem BUT the 64 writelanes into
//        one dst register form a 64-deep serial RMW chain -> 84.4us. Stall-
//        bound, not issue-bound: chain depth beat instruction count.
//   R14: v_cmp_lt_f32 -> arbitrary SGPR pair (VOP3; the C "(a<b)?1:0" form
//        serializes through the single vcc), then v_addc_co_u32 with that
//        pair as carry-in: p += (elem < val) in 2 VALU ops, 4 independent
//        16-deep chains per row (8 across the row pair). cmp/addc are
//        separate asm statements so the scheduler interleaves chains.
//   Rest identical to R13: 2-row pipelining, double-slot ubuf, one lgkm
//   drain per pair, pass1 on global uniform float4 (vmem pipe), pass2 on
//   LDS b128 broadcasts (lds pipe).

#define RANK1(dst, val, elem)                              \
    do {                                                   \
        unsigned long long _m;                             \
        asm("v_cmp_lt_f32 %0, %1, %2"                      \
            : "=s"(_m)                                     \
            : "v"(elem), "v"(val));                        \
        asm("v_addc_co_u32 %0, %1, %0, 0, %1"              \
            : "+v"(dst), "+s"(_m));                        \
    } while (0)

#define RANK4(d0, d1, d2, d3, val, a)   \
    do {                                \
        RANK1(d0, val, (a).x);          \
        RANK1(d1, val, (a).y);          \
        RANK1(d2, val, (a).z);          \
        RANK1(d3, val, (a).w);          \
    } while (0)

__global__ __launch_bounds__(256) void mmrl_partial(const float* __restrict__ scores,
                                                    const float* __restrict__ labels,
                                                    float* __restrict__ partial,
                                                    int rows) {
    __shared__ float ubuf[WAVES_PER_BLOCK][2][N];
    __shared__ float wsum[WAVES_PER_BLOCK];

    const int lane = threadIdx.x & 63;
    const int w    = threadIdx.x >> 6;
    const int gwave = blockIdx.x * WAVES_PER_BLOCK + w;
    const int nwaves = NBLOCKS * WAVES_PER_BLOCK;

    float acc = 0.0f;

    int row = gwave;

    // ---- paired rows: 8 independent chains for ILP, one lgkm drain per pair ----
    for (; row + nwaves < rows; row += 2 * nwaves) {
        const int base0 = __builtin_amdgcn_readfirstlane(row) * N;
        const int base1 = base0 + nwaves * N;

        const float labv0 = labels[base0 + lane];   // coalesced per-lane copy
        const float scv0  = scores[base0 + lane];
        const float labv1 = labels[base1 + lane];
        const float scv1  = scores[base1 + lane];

        const float4* L40 = (const float4*)(labels + base0);  // uniform broadcasts
        const float4* L41 = (const float4*)(labels + base1);

        // ---- pass 1: label ranks p (cmp->sgpr pair, addc carry-in) ----
        int p00 = 0, p01 = 0, p02 = 0, p03 = 0;
        int p10 = 0, p11 = 0, p12 = 0, p13 = 0;
        #pragma unroll
        for (int kk = 0; kk < N / 4; ++kk) {
            const float4 a0 = L40[kk];
            RANK4(p00, p01, p02, p03, labv0, a0);
            const float4 a1 = L41[kk];
            RANK4(p10, p11, p12, p13, labv1, a1);
        }
        const int pv0 = (p00 + p01) + (p02 + p03);
        const int pv1 = (p10 + p11) + (p12 + p13);

        const float u0 = fmaf(-MARGIN, (float)pv0, scv0);
        const float u1 = fmaf(-MARGIN, (float)pv1, scv1);
        ubuf[w][0][lane] = u0;
        ubuf[w][1][lane] = u1;
        asm volatile("s_waitcnt lgkmcnt(0)" ::: "memory");  // intra-wave LDS in-order

        // ---- pass 2: u ranks q (LDS uniform float4 broadcasts) ----
        const float4* U40 = (const float4*)ubuf[w][0];
        const float4* U41 = (const float4*)ubuf[w][1];
        int q00 = 0, q01 = 0, q02 = 0, q03 = 0;
        int q10 = 0, q11 = 0, q12 = 0, q13 = 0;
        #pragma unroll
        for (int kk = 0; kk < N / 4; ++kk) {
            const float4 b0 = U40[kk];
            RANK4(q00, q01, q02, q03, u0, b0);
            const float4 b1 = U41[kk];
            RANK4(q10, q11, q12, q13, u1, b1);
        }
        const int qv0 = (q00 + q01) + (q02 + q03);
        const int qv1 = (q10 + q11) + (q12 + q13);

        acc = fmaf(u0, (float)(qv0 - pv0), acc);
        acc = fmaf(u1, (float)(qv1 - pv1), acc);
    }

    // ---- tail: single row (generic; not hit for rows=32768, nwaves=8192) ----
    for (; row < rows; row += nwaves) {
        const int base = __builtin_amdgcn_readfirstlane(row) * N;
        const float labv = labels[base + lane];
        const float scv  = scores[base + lane];
        const float4* L4 = (const float4*)(labels + base);

        int p0 = 0, p1 = 0, p2 = 0, p3 = 0;
        #pragma unroll
        for (int kk = 0; kk < N / 4; ++kk) {
            const float4 a = L4[kk];
            RANK4(p0, p1, p2, p3, labv, a);
        }
        const int pv = (p0 + p1) + (p2 + p3);

        const float u = fmaf(-MARGIN, (float)pv, scv);
        ubuf[w][0][lane] = u;
        asm volatile("s_waitcnt lgkmcnt(0)" ::: "memory");

        const float4* U4 = (const float4*)ubuf[w][0];
        int q0 = 0, q1 = 0, q2 = 0, q3 = 0;
        #pragma unroll
        for (int kk = 0; kk < N / 4; ++kk) {
            const float4 b = U4[kk];
            RANK4(q0, q1, q2, q3, u, b);
        }
        const int qv = (q0 + q1) + (q2 + q3);

        acc = fmaf(u, (float)(qv - pv), acc);
    }

    // ---- wave reduction ----
    #pragma unroll
    for (int off = 32; off > 0; off >>= 1)
        acc += __shfl_down(acc, off, 64);

    if (lane == 0) wsum[w] = acc;
    __syncthreads();
    if (threadIdx.x == 0) {
        float s = 0.0f;
        #pragma unroll
        for (int i = 0; i < WAVES_PER_BLOCK; ++i) s += wsum[i];
        partial[blockIdx.x] = s;          // plain store, no atomic, no fence
    }
}

__global__ __launch_bounds__(256) void mmrl_reduce(const float* __restrict__ partial,
                                                   float* __restrict__ out,
                                                   int npartial, float inv_rows) {
    const int t = threadIdx.x;
    float s = 0.0f;
    for (int i = t; i < npartial; i += 256)
        s += partial[i];
    #pragma unroll
    for (int off = 32; off > 0; off >>= 1)
        s += __shfl_down(s, off, 64);
    __shared__ float wsum[4];
    if ((t & 63) == 0) wsum[t >> 6] = s;
    __syncthreads();
    if (t == 0)
        out[0] = (wsum[0] + wsum[1] + wsum[2] + wsum[3]) * inv_rows;
}

extern "C" void kernel_launch(void* const* d_in, const int* in_sizes, int n_in,
                              void* d_out, int out_size, void* d_ws, size_t ws_size,
                              hipStream_t stream) {
    const float* scores = (const float*)d_in[0];
    const float* labels = (const float*)d_in[1];
    float* out = (float*)d_out;
    float* partial = (float*)d_ws;        // 2048 floats = 8 KB << ws_size
    const int rows = in_sizes[0] / N;     // 32768

    mmrl_partial<<<NBLOCKS, 256, 0, stream>>>(scores, labels, partial, rows);
    mmrl_reduce<<<1, 256, 0, stream>>>(partial, out, NBLOCKS, 1.0f / (float)rows);
}